// Round 4
// baseline (407.772 us; speedup 1.0000x reference)
//
#include <hip/hip_runtime.h>

// ---------------------------------------------------------------------------
// GNN predictor (fp32 I/O). Round 13 = Round-12 kernel resubmitted: the R3
// bench died at container acquire ("failed twice", no timing/pytest fields)
// => infra failure, kernel never ran. Source re-audited: scatter slots
// provably in [0,E), graph-replay re-init clean, ws ~53MB (< R2's 85MB).
// Only change: defensive slot<E clamp in k_scatter.
//
// Structure: Round 11 fused/node kernels (fused verified 69.2us) + direct
// per-node CSR build replacing the 2-pass bucket sort:
//   count:   atomicAdd(deg[dst])          1.6M atomics over 400KB
//   scan:    per-256-block LDS scan + one galloc atomic per block -> seg,cursor
//   scatter: slot=atomicAdd(cursor[dst]); ssrc[slot]=src   (one 4B scatter)
// Non-deterministic region placement is fine: regions disjoint; fp-sum order
// in fused was already non-deterministic.
// Round-10 LESSON: single global-cursor dynamic chunking REGRESSED 4.5x
// (25000 same-line dependent atomics serialize; VALUBusy 68->12%). Static
// 13-node/wave partition has only +/-7% Poisson imbalance. No global cursor
// in the hot kernel.
// Round-8 LESSON: 64KB-LDS bucket fusion regressed 3x; do not re-fuse below
// ~8 waves/CU.
// Fused-kernel VALU diet (verified R11): tanh scale folded into W2e/b2e;
// sum tanh = deg - 2*sum sigma; pairwise rcp; full/tail batch split.
// ---------------------------------------------------------------------------

#define LRELU_SLOPE 0.01f
#define TANH_SCALE 2.8853900817779268f  // 2*log2(e), folded into W2e/b2e

constexpr int OFF_W1ET  = 0;          // [32][76]  edge W1 transposed
constexpr int OFF_B1E   = 2432;       // [32]
constexpr int OFF_B2E   = 4512;       // [64]      pre-scaled by TANH_SCALE
constexpr int OFF_W1NA  = 4576;       // [32][76]  node W1 (pos,u,h dims) in x76 order
constexpr int OFF_W1NS  = 7008;       // [32][64]  node W1 (sumh dims) transposed
constexpr int OFF_W2N   = 9056;       // [32][64]
constexpr int OFF_B2N   = 11104;      // [64]
constexpr int OFF_B1N   = 11168;      // [32]
constexpr int OFF_W1POS = 11200;      // [32] float2 (W1e rows 2,3)
constexpr int W_TOTAL   = 11264;

typedef __bf16 bf16x8 __attribute__((ext_vector_type(8)));
typedef float  f32x4  __attribute__((ext_vector_type(4)));

__device__ __forceinline__ float ftanh(float x) {
    float e = __builtin_amdgcn_exp2f(x * 2.8853900817779268f);
    return 1.0f - 2.0f * __builtin_amdgcn_rcpf(e + 1.0f);
}
__device__ __forceinline__ unsigned f2bf_pair(float f0, float f1) {
    unsigned u0 = __float_as_uint(f0), u1 = __float_as_uint(f1);
    unsigned r0 = (u0 + 0x7fffu + ((u0 >> 16) & 1u)) >> 16;   // RNE
    unsigned r1 = (u1 + 0x7fffu + ((u1 >> 16) & 1u)) >> 16;
    return r0 | (r1 << 16);
}
__device__ __forceinline__ float bf_lo(unsigned p) { return __uint_as_float(p << 16); }
__device__ __forceinline__ float bf_hi(unsigned p) { return __uint_as_float(p & 0xffff0000u); }

// ---------------------------------------------------------------------------
__global__ void prep_weights(const float* __restrict__ W1e, const float* __restrict__ b1e,
                             const float* __restrict__ W2e, const float* __restrict__ b2e,
                             const float* __restrict__ W1n, const float* __restrict__ b1n,
                             const float* __restrict__ W2n, const float* __restrict__ b2n,
                             float* __restrict__ Wf, uint4* __restrict__ fragW2,
                             int* __restrict__ deg, int* __restrict__ galloc, int N) {
    int t = blockIdx.x * blockDim.x + threadIdx.x;
    int T = gridDim.x * blockDim.x;
    if (t == 0) *galloc = 0;
    for (int idx = t; idx < N; idx += T) deg[idx] = 0;
    for (int idx = t; idx < 2432; idx += T) {            // W1e [76][32] -> [32][76]
        int i = idx / 32, j = idx % 32;
        Wf[OFF_W1ET + j * 76 + i] = W1e[idx];
    }
    for (int idx = t; idx < 32; idx += T)   Wf[OFF_B1E + idx] = b1e[idx];
    for (int idx = t; idx < 64; idx += T)   Wf[OFF_B2E + idx] = b2e[idx] * TANH_SCALE;
    // W1NA[j][i]: node-layer1 weights for x76 = [pos(2),0,0,u(8),h(64)]
    for (int idx = t; idx < 2432; idx += T) {
        int j = idx / 76, i = idx % 76;
        float v = 0.f;
        if (i < 2)                 v = W1n[i * 32 + j];
        else if (i >= 4 && i < 12) v = W1n[(130 + (i - 4)) * 32 + j];
        else if (i >= 12)          v = W1n[(2 + (i - 12)) * 32 + j];
        Wf[OFF_W1NA + idx] = v;
    }
    for (int idx = t; idx < 2048; idx += T) {            // W1NS [32][64]
        int j = idx / 64, k = idx % 64;
        Wf[OFF_W1NS + idx] = W1n[(66 + k) * 32 + j];
    }
    for (int idx = t; idx < 2048; idx += T) Wf[OFF_W2N + idx] = W2n[idx];
    for (int idx = t; idx < 64; idx += T)   Wf[OFF_B2N + idx] = b2n[idx];
    for (int idx = t; idx < 32; idx += T)   Wf[OFF_B1N + idx] = b1n[idx];
    for (int idx = t; idx < 32; idx += T) {
        Wf[OFF_W1POS + 2 * idx + 0] = W1e[2 * 32 + idx];
        Wf[OFF_W1POS + 2 * idx + 1] = W1e[3 * 32 + idx];
    }
    // MFMA B-fragments for W2e (bf16, pre-scaled), 4 N-tiles x 64 lanes x 16B
    for (int idx = t; idx < 256; idx += T) {
        int tt = idx >> 6, l = idx & 63;
        int colv = l & 15, quadv = l >> 4;
        uint4 v;
        unsigned pk[4];
#pragma unroll
        for (int pr = 0; pr < 4; pr++) {
            int j0 = quadv * 8 + 2 * pr;
            float f0 = W2e[j0 * 64 + 16 * tt + colv] * TANH_SCALE;
            float f1 = W2e[(j0 + 1) * 64 + 16 * tt + colv] * TANH_SCALE;
            pk[pr] = f2bf_pair(f0, f1);
        }
        v.x = pk[0]; v.y = pk[1]; v.z = pk[2]; v.w = pk[3];
        fragW2[tt * 64 + l] = v;
    }
}

// ---------------------------------------------------------------------------
// Phase 1: degree count (blocks < nblkA) + per-node precompute (rest):
//   Abf[n][32] bf16 : edge-MLP layer1 src part
//   A2 [n][32] f32  : node-MLP layer1 pos/h/u part (+b1n)
// ---------------------------------------------------------------------------
__global__ __launch_bounds__(256) void k_phase1(
    const float* __restrict__ hbuf, const float* __restrict__ ubuf,
    const float* __restrict__ posbuf, const float* __restrict__ Wf,
    uint4* __restrict__ Abf, float* __restrict__ A2,
    const int* __restrict__ dst, int* __restrict__ deg,
    int E, int N, int nblkA) {
    int tid = threadIdx.x;
    if ((int)blockIdx.x < nblkA) {
        int e0 = blockIdx.x * 4096;
#pragma unroll
        for (int k = 0; k < 16; k++) {
            int e = e0 + k * 256 + tid;
            if (e < E) atomicAdd(&deg[dst[e]], 1);
        }
        return;
    }
    // ---- per-node precompute ----
    int n = (blockIdx.x - nblkA) * 256 + tid;
    if (n >= N) return;
    float x[76];
    float2 pp = ((const float2*)posbuf)[n];
    x[0] = pp.x; x[1] = pp.y; x[2] = 0.f; x[3] = 0.f;
    const float4* u4 = (const float4*)ubuf;
#pragma unroll
    for (int c = 0; c < 2; c++) {
        float4 uu = u4[(size_t)n * 2 + c];
        int b = 4 + 4 * c;
        x[b] = uu.x; x[b + 1] = uu.y; x[b + 2] = uu.z; x[b + 3] = uu.w;
    }
    const float4* h4 = (const float4*)hbuf;
#pragma unroll
    for (int c = 0; c < 16; c++) {
        float4 hh = h4[(size_t)n * 16 + c];
        int b = 12 + 4 * c;
        x[b] = hh.x; x[b + 1] = hh.y; x[b + 2] = hh.z; x[b + 3] = hh.w;
    }
    float ar[32];
#pragma unroll 1
    for (int j = 0; j < 32; j++) {
        const float* w1 = Wf + OFF_W1ET + j * 76;
        float a0 = Wf[OFF_B1E + j], a1 = 0.f, a2 = 0.f, a3 = 0.f;
#pragma unroll
        for (int i = 0; i < 76; i += 4) {
            a0 = fmaf(x[i + 0], w1[i + 0], a0);
            a1 = fmaf(x[i + 1], w1[i + 1], a1);
            a2 = fmaf(x[i + 2], w1[i + 2], a2);
            a3 = fmaf(x[i + 3], w1[i + 3], a3);
        }
        ar[j] = (a0 + a1) + (a2 + a3);
    }
#pragma unroll
    for (int c = 0; c < 4; c++) {
        uint4 v;
        v.x = f2bf_pair(ar[8 * c + 0], ar[8 * c + 1]);
        v.y = f2bf_pair(ar[8 * c + 2], ar[8 * c + 3]);
        v.z = f2bf_pair(ar[8 * c + 4], ar[8 * c + 5]);
        v.w = f2bf_pair(ar[8 * c + 6], ar[8 * c + 7]);
        Abf[(size_t)n * 4 + c] = v;
    }
    // node-MLP layer1 pos/h/u part (x[2],x[3] are zero -> harmless)
#pragma unroll 1
    for (int j = 0; j < 32; j++) {
        const float* w1 = Wf + OFF_W1NA + j * 76;
        float a0 = Wf[OFF_B1N + j], a1 = 0.f, a2 = 0.f, a3 = 0.f;
#pragma unroll
        for (int i = 0; i < 76; i += 4) {
            a0 = fmaf(x[i + 0], w1[i + 0], a0);
            a1 = fmaf(x[i + 1], w1[i + 1], a1);
            a2 = fmaf(x[i + 2], w1[i + 2], a2);
            a3 = fmaf(x[i + 3], w1[i + 3], a3);
        }
        ar[j] = (a0 + a1) + (a2 + a3);
    }
#pragma unroll
    for (int c = 0; c < 8; c++) {
        float4 v; v.x = ar[4 * c]; v.y = ar[4 * c + 1];
        v.z = ar[4 * c + 2]; v.w = ar[4 * c + 3];
        ((float4*)(A2 + (size_t)n * 32))[c] = v;
    }
}

// ---------------------------------------------------------------------------
// Scan: one block per 256 nodes. LDS scan of deg -> per-node (lo,hi) via one
// galloc atomic per block (391 total; placement non-deterministic but
// regions disjoint).
// ---------------------------------------------------------------------------
__global__ __launch_bounds__(256) void k_scan(
    const int* __restrict__ deg, int* __restrict__ galloc,
    int2* __restrict__ seg, int* __restrict__ cursor, int N) {
    __shared__ int scn[256];
    __shared__ int sbase;
    int tid = threadIdx.x;
    int n = blockIdx.x * 256 + tid;
    int d = (n < N) ? deg[n] : 0;
    scn[tid] = d;
    __syncthreads();
    for (int st = 1; st < 256; st <<= 1) {
        int add = (tid >= st) ? scn[tid - st] : 0;
        __syncthreads();
        scn[tid] += add;
        __syncthreads();
    }
    if (tid == 255) sbase = atomicAdd(galloc, scn[255]);
    __syncthreads();
    int lo = sbase + scn[tid] - d;
    if (n < N) {
        seg[n] = make_int2(lo, lo + d);
        cursor[n] = lo;
    }
}

// ---------------------------------------------------------------------------
// Scatter: slot = atomicAdd(cursor[dst]); ssrc[slot] = src. One 4B scatter
// per edge (pairbuf round-trip eliminated). slot provably < E; clamp is
// pure defense.
// ---------------------------------------------------------------------------
__global__ __launch_bounds__(256) void k_scatter(
    const int* __restrict__ src, const int* __restrict__ dst,
    int* __restrict__ cursor, int* __restrict__ ssrc, int E) {
    int tid = threadIdx.x;
    int e0 = blockIdx.x * 4096;
#pragma unroll
    for (int k = 0; k < 16; k++) {
        int e = e0 + k * 256 + tid;
        if (e < E) {
            int slot = atomicAdd(&cursor[dst[e]], 1);
            if (slot < E) ssrc[slot] = src[e];
        }
    }
}

// ---------------------------------------------------------------------------
// Fused edge-MLP + gather: each wave owns a contiguous node range; manual
// prefetch of next batch's ssrc/Abf overlaps the dependent-load chain with
// the current batch's MFMA + sigmoid-sum epilogue.
// sum tanh = deg - 2*sum sigma; W2e/b2e pre-scaled by 2*log2(e) so exp2
// takes the MFMA acc directly; pairwise rcp halves the rcp count; full
// batches are mask-free (only the <=1 tail batch per node masks rows).
// ---------------------------------------------------------------------------
__global__ __launch_bounds__(256) void fused_edge_gather(
    const int2* __restrict__ seg, const int* __restrict__ ssrc,
    const uint4* __restrict__ Abf, const float* __restrict__ posbuf,
    const float* __restrict__ Wf, const uint4* __restrict__ fragW2,
    float* __restrict__ sumh, int N, int npw) {
    int wid = blockIdx.x * 4 + (threadIdx.x >> 6);
    int lane = threadIdx.x & 63;
    int col = lane & 15, quad = lane >> 4;

    union { uint4 u; bf16x8 v; } cvt;
    bf16x8 bfr[4];
#pragma unroll
    for (int t = 0; t < 4; t++) {
        cvt.u = fragW2[t * 64 + lane];
        bfr[t] = cvt.v;
    }
    float c0[4];
#pragma unroll
    for (int t = 0; t < 4; t++) c0[t] = Wf[OFF_B2E + 16 * t + col];
    float wx[8], wy[8];
#pragma unroll
    for (int jj = 0; jj < 8; jj++) {
        float2 wv = ((const float2*)(Wf + OFF_W1POS))[quad * 8 + jj];
        wx[jj] = wv.x; wy[jj] = wv.y;
    }

    int n0 = wid * npw;
    int n1 = n0 + npw; n1 = (n1 < N) ? n1 : N;
#pragma unroll 1
    for (int n = n0; n < n1; n++) {
        int2 sg = seg[n];
        int lo = sg.x, hi = sg.y, deg = hi - lo;
        float2 pd = ((const float2*)posbuf)[n];
        float padd[8];
#pragma unroll
        for (int jj = 0; jj < 8; jj++)
            padd[jj] = fmaf(pd.x, wx[jj], pd.y * wy[jj]);

        float s0[4] = {0.f, 0.f, 0.f, 0.f};
        if (deg > 0) {
            int te = lo + col;
            te = (te < hi) ? te : (hi - 1);
            uint4 ar = Abf[(size_t)ssrc[te] * 4 + quad];
            int nfull = deg & ~15;
#pragma unroll 1
            for (int b = 0; b < nfull; b += 16) {
                // prefetch next batch (clamped; harmless re-read at the end)
                int teN = lo + b + 16 + col;
                teN = (teN < hi) ? teN : (hi - 1);
                uint4 arN = Abf[(size_t)ssrc[teN] * 4 + quad];

                bf16x8 af;
                {
                    float v0 = bf_lo(ar.x) + padd[0], v1 = bf_hi(ar.x) + padd[1];
                    float v2 = bf_lo(ar.y) + padd[2], v3 = bf_hi(ar.y) + padd[3];
                    float v4 = bf_lo(ar.z) + padd[4], v5 = bf_hi(ar.z) + padd[5];
                    float v6 = bf_lo(ar.w) + padd[6], v7 = bf_hi(ar.w) + padd[7];
                    v0 = fmaxf(v0, LRELU_SLOPE * v0); v1 = fmaxf(v1, LRELU_SLOPE * v1);
                    v2 = fmaxf(v2, LRELU_SLOPE * v2); v3 = fmaxf(v3, LRELU_SLOPE * v3);
                    v4 = fmaxf(v4, LRELU_SLOPE * v4); v5 = fmaxf(v5, LRELU_SLOPE * v5);
                    v6 = fmaxf(v6, LRELU_SLOPE * v6); v7 = fmaxf(v7, LRELU_SLOPE * v7);
                    af[0] = (__bf16)v0; af[1] = (__bf16)v1; af[2] = (__bf16)v2; af[3] = (__bf16)v3;
                    af[4] = (__bf16)v4; af[5] = (__bf16)v5; af[6] = (__bf16)v6; af[7] = (__bf16)v7;
                }
#pragma unroll
                for (int t = 0; t < 4; t++) {
                    f32x4 acc = {c0[t], c0[t], c0[t], c0[t]};
                    acc = __builtin_amdgcn_mfma_f32_16x16x32_bf16(af, bfr[t], acc, 0, 0, 0);
                    float u0 = __builtin_amdgcn_exp2f(acc[0]);
                    float u1 = __builtin_amdgcn_exp2f(acc[1]);
                    float u2 = __builtin_amdgcn_exp2f(acc[2]);
                    float u3 = __builtin_amdgcn_exp2f(acc[3]);
                    float q01 = u0 + u1, q23 = u2 + u3;
                    float d01 = fmaf(u0, u1, q01) + 1.f;
                    float d23 = fmaf(u2, u3, q23) + 1.f;
                    s0[t] = fmaf(q01 + 2.f, __builtin_amdgcn_rcpf(d01), s0[t]);
                    s0[t] = fmaf(q23 + 2.f, __builtin_amdgcn_rcpf(d23), s0[t]);
                }
                ar = arN;
            }
            int tail = deg - nfull;
            if (tail) {
                bf16x8 af;
                {
                    float v0 = bf_lo(ar.x) + padd[0], v1 = bf_hi(ar.x) + padd[1];
                    float v2 = bf_lo(ar.y) + padd[2], v3 = bf_hi(ar.y) + padd[3];
                    float v4 = bf_lo(ar.z) + padd[4], v5 = bf_hi(ar.z) + padd[5];
                    float v6 = bf_lo(ar.w) + padd[6], v7 = bf_hi(ar.w) + padd[7];
                    v0 = fmaxf(v0, LRELU_SLOPE * v0); v1 = fmaxf(v1, LRELU_SLOPE * v1);
                    v2 = fmaxf(v2, LRELU_SLOPE * v2); v3 = fmaxf(v3, LRELU_SLOPE * v3);
                    v4 = fmaxf(v4, LRELU_SLOPE * v4); v5 = fmaxf(v5, LRELU_SLOPE * v5);
                    v6 = fmaxf(v6, LRELU_SLOPE * v6); v7 = fmaxf(v7, LRELU_SLOPE * v7);
                    af[0] = (__bf16)v0; af[1] = (__bf16)v1; af[2] = (__bf16)v2; af[3] = (__bf16)v3;
                    af[4] = (__bf16)v4; af[5] = (__bf16)v5; af[6] = (__bf16)v6; af[7] = (__bf16)v7;
                }
                int rowb = quad * 4;
#pragma unroll
                for (int t = 0; t < 4; t++) {
                    f32x4 acc = {c0[t], c0[t], c0[t], c0[t]};
                    acc = __builtin_amdgcn_mfma_f32_16x16x32_bf16(af, bfr[t], acc, 0, 0, 0);
                    // invalid rows: u = 1e30 -> pair algebra makes the
                    // contribution ~2^-60 (drops out); double-invalid ~0.
                    float u0 = (rowb + 0 < tail) ? __builtin_amdgcn_exp2f(acc[0]) : 1e30f;
                    float u1 = (rowb + 1 < tail) ? __builtin_amdgcn_exp2f(acc[1]) : 1e30f;
                    float u2 = (rowb + 2 < tail) ? __builtin_amdgcn_exp2f(acc[2]) : 1e30f;
                    float u3 = (rowb + 3 < tail) ? __builtin_amdgcn_exp2f(acc[3]) : 1e30f;
                    float q01 = u0 + u1, q23 = u2 + u3;
                    float d01 = fmaf(u0, u1, q01) + 1.f;
                    float d23 = fmaf(u2, u3, q23) + 1.f;
                    s0[t] = fmaf(q01 + 2.f, __builtin_amdgcn_rcpf(d01), s0[t]);
                    s0[t] = fmaf(q23 + 2.f, __builtin_amdgcn_rcpf(d23), s0[t]);
                }
            }
        }
#pragma unroll
        for (int t = 0; t < 4; t++) {
            s0[t] += __shfl_xor(s0[t], 16);
            s0[t] += __shfl_xor(s0[t], 32);
        }
        if (lane < 16) {
            float* sr = sumh + (size_t)n * 64;
            float fd = (float)deg;
#pragma unroll
            for (int t = 0; t < 4; t++) sr[16 * t + lane] = fmaf(-2.f, s0[t], fd);
        }
    }
}

// ---------------------------------------------------------------------------
// Node kernel (factored): y = A2[n] + W1NS^T . sumh[n]; o = W2n^T . lrelu(y)
// ---------------------------------------------------------------------------
__global__ __launch_bounds__(256) void k_node2(
    const float* __restrict__ A2, const float* __restrict__ sumh,
    const float* __restrict__ Wf, float* __restrict__ out, int N) {
    int n = blockIdx.x * blockDim.x + threadIdx.x;
    if (n >= N) return;

    float s[64];
    const float4* s4 = (const float4*)(sumh + (size_t)n * 64);
#pragma unroll
    for (int c = 0; c < 16; c++) {
        float4 v = s4[c];
        s[4 * c] = v.x; s[4 * c + 1] = v.y; s[4 * c + 2] = v.z; s[4 * c + 3] = v.w;
    }

    float o[64];
#pragma unroll
    for (int k = 0; k < 64; k++) o[k] = Wf[OFF_B2N + k];

    const float4* a24 = (const float4*)(A2 + (size_t)n * 32);
#pragma unroll 1
    for (int jj = 0; jj < 8; jj++) {
        float4 av = a24[jj];
#pragma unroll
        for (int q = 0; q < 4; q++) {
            int j = jj * 4 + q;
            const float* w1 = Wf + OFF_W1NS + j * 64;   // uniform -> s_load
            float a0 = (q == 0) ? av.x : (q == 1) ? av.y : (q == 2) ? av.z : av.w;
            float a1 = 0.f, a2 = 0.f, a3 = 0.f;
#pragma unroll
            for (int i = 0; i < 64; i += 4) {
                a0 = fmaf(s[i + 0], w1[i + 0], a0);
                a1 = fmaf(s[i + 1], w1[i + 1], a1);
                a2 = fmaf(s[i + 2], w1[i + 2], a2);
                a3 = fmaf(s[i + 3], w1[i + 3], a3);
            }
            float y = (a0 + a1) + (a2 + a3);
            y = (y >= 0.f) ? y : LRELU_SLOPE * y;
            const float* w2 = Wf + OFF_W2N + j * 64;    // uniform -> s_load
#pragma unroll
            for (int k = 0; k < 64; k++) o[k] = fmaf(y, w2[k], o[k]);
        }
    }

    float4* orow = (float4*)(out + (size_t)n * 64);
#pragma unroll
    for (int c = 0; c < 16; c++) {
        float4 v;
        v.x = ftanh(o[4 * c + 0]); v.y = ftanh(o[4 * c + 1]);
        v.z = ftanh(o[4 * c + 2]); v.w = ftanh(o[4 * c + 3]);
        orow[c] = v;
    }
}

// ---------------------------------------------------------------------------
extern "C" void kernel_launch(void* const* d_in, const int* in_sizes, int n_in,
                              void* d_out, int out_size, void* d_ws, size_t ws_size,
                              hipStream_t stream) {
    const float* hbuf   = (const float*)d_in[0];
    const float* ubuf   = (const float*)d_in[1];
    const float* posbuf = (const float*)d_in[2];
    const int* src = (const int*)d_in[3];
    const int* dst = (const int*)d_in[4];

    int N = in_sizes[0] / 64;
    int E = in_sizes[3];
    int NBLK256 = (N + 255) / 256;
    int nblkA = (E + 4095) / 4096;

    char* p = (char*)d_ws;
    auto alloc = [&](size_t bytes) {
        char* r = p;
        p += (bytes + 255) & ~(size_t)255;
        return r;
    };
    float*    Wf      = (float*)alloc(W_TOTAL * 4);
    uint4*    fragW2  = (uint4*)alloc(4 * 64 * 16);
    uint4*    Abf     = (uint4*)alloc((size_t)N * 64);   // bf16 A rows, 64B
    float*    A2      = (float*)alloc((size_t)N * 32 * 4);
    float*    sumh    = (float*)alloc((size_t)N * 64 * 4);
    int2*     seg     = (int2*)alloc((size_t)N * 8);
    int*      deg     = (int*)alloc((size_t)N * 4);
    int*      cursor  = (int*)alloc((size_t)N * 4);
    int*      galloc  = (int*)alloc(256);
    int*      ssrc    = (int*)alloc((size_t)E * 4);

    prep_weights<<<32, 256, 0, stream>>>(
        (const float*)d_in[5], (const float*)d_in[6],
        (const float*)d_in[7], (const float*)d_in[8],
        (const float*)d_in[9], (const float*)d_in[10],
        (const float*)d_in[11], (const float*)d_in[12], Wf, fragW2,
        deg, galloc, N);

    k_phase1<<<nblkA + NBLK256, 256, 0, stream>>>(
        hbuf, ubuf, posbuf, Wf, Abf, A2, dst, deg, E, N, nblkA);

    k_scan<<<NBLK256, 256, 0, stream>>>(deg, galloc, seg, cursor, N);

    k_scatter<<<nblkA, 256, 0, stream>>>(src, dst, cursor, ssrc, E);

    const int FBLK = 2048;                    // 8192 waves = full machine
    int npw = (N + FBLK * 4 - 1) / (FBLK * 4);
    fused_edge_gather<<<FBLK, 256, 0, stream>>>(
        seg, ssrc, Abf, posbuf, Wf, fragW2, sumh, N, npw);

    k_node2<<<(N + 255) / 256, 256, 0, stream>>>(
        A2, sumh, Wf, (float*)d_out, N);
}

// Round 5
// 288.425 us; speedup vs baseline: 1.4138x; 1.4138x over previous
//
#include <hip/hip_runtime.h>

// ---------------------------------------------------------------------------
// GNN predictor (fp32 I/O). Round 14 = Round-11 pipeline (best verified:
// 285.5us total, fused 69.2us) with the node-MLP FOLDED into the fused
// kernel's epilogue: k_node2 and the sumh round-trip (25.6MB w + 25.6MB r)
// are gone. Per node, after the shfl-reduce the wave holds the 64-dim sum;
// W1NS/W2n^T staged in LDS (bank-conflict pads 66/34), lanes 0-31 do
// layer-1, all 64 lanes do one output dim each + tanh + coalesced store.
//
// R12/R13 LESSON (measured R4): per-edge device-scope atomics scatter
// (atomicAdd(deg[dst]), cursor[dst]) = memory-side ~64B RMW each on
// non-coherent-L2 MI355X: k_phase1 107us, +49MB write traffic, VALUBusy 7%.
// LDS-aggregated histogram (pairbuf 2-pass bucket sort) is the right
// pattern -- reverted to it.
// Round-10 LESSON: single global-cursor dynamic chunking REGRESSED 4.5x
// (serialized same-line dependent atomics). Static node partition only.
// Round-8 LESSON: 64KB-LDS bucket fusion regressed 3x; don't re-fuse the
// GATHER below ~8 waves/CU (this round's epilogue fold keeps the edge loop
// structure intact and runs at 24+ waves/CU).
// Fused VALU diet (verified R11): tanh scale folded into W2e/b2e;
// sum tanh = deg - 2*sum sigma; pairwise rcp; full/tail batch split.
// ---------------------------------------------------------------------------

#define LRELU_SLOPE 0.01f
#define BUCK_SHIFT 8                  // 256 nodes per bucket
#define TANH_SCALE 2.8853900817779268f  // 2*log2(e), folded into W2e/b2e

constexpr int OFF_W1ET  = 0;          // [32][76]  edge W1 transposed
constexpr int OFF_B1E   = 2432;       // [32]
constexpr int OFF_B2E   = 4512;       // [64]      pre-scaled by TANH_SCALE
constexpr int OFF_W1NA  = 4576;       // [32][76]  node W1 (pos,u,h dims) in x76 order
constexpr int OFF_W1NS  = 7008;       // [32][64]  node W1 (sumh dims) transposed
constexpr int OFF_W2N   = 9056;       // [32][64]
constexpr int OFF_B2N   = 11104;      // [64]
constexpr int OFF_B1N   = 11168;      // [32]
constexpr int OFF_W1POS = 11200;      // [32] float2 (W1e rows 2,3)
constexpr int W_TOTAL   = 11264;

typedef __bf16 bf16x8 __attribute__((ext_vector_type(8)));
typedef float  f32x4  __attribute__((ext_vector_type(4)));

__device__ __forceinline__ float ftanh(float x) {
    float e = __builtin_amdgcn_exp2f(x * 2.8853900817779268f);
    return 1.0f - 2.0f * __builtin_amdgcn_rcpf(e + 1.0f);
}
__device__ __forceinline__ unsigned f2bf_pair(float f0, float f1) {
    unsigned u0 = __float_as_uint(f0), u1 = __float_as_uint(f1);
    unsigned r0 = (u0 + 0x7fffu + ((u0 >> 16) & 1u)) >> 16;   // RNE
    unsigned r1 = (u1 + 0x7fffu + ((u1 >> 16) & 1u)) >> 16;
    return r0 | (r1 << 16);
}
__device__ __forceinline__ float bf_lo(unsigned p) { return __uint_as_float(p << 16); }
__device__ __forceinline__ float bf_hi(unsigned p) { return __uint_as_float(p & 0xffff0000u); }

// ---------------------------------------------------------------------------
__global__ void prep_weights(const float* __restrict__ W1e, const float* __restrict__ b1e,
                             const float* __restrict__ W2e, const float* __restrict__ b2e,
                             const float* __restrict__ W1n, const float* __restrict__ b1n,
                             const float* __restrict__ W2n, const float* __restrict__ b2n,
                             float* __restrict__ Wf, uint4* __restrict__ fragW2,
                             int* __restrict__ gcnt, int nbuck) {
    int t = blockIdx.x * blockDim.x + threadIdx.x;
    int T = gridDim.x * blockDim.x;
    for (int idx = t; idx < nbuck; idx += T) gcnt[idx] = 0;
    for (int idx = t; idx < 2432; idx += T) {            // W1e [76][32] -> [32][76]
        int i = idx / 32, j = idx % 32;
        Wf[OFF_W1ET + j * 76 + i] = W1e[idx];
    }
    for (int idx = t; idx < 32; idx += T)   Wf[OFF_B1E + idx] = b1e[idx];
    for (int idx = t; idx < 64; idx += T)   Wf[OFF_B2E + idx] = b2e[idx] * TANH_SCALE;
    // W1NA[j][i]: node-layer1 weights for x76 = [pos(2),0,0,u(8),h(64)]
    for (int idx = t; idx < 2432; idx += T) {
        int j = idx / 76, i = idx % 76;
        float v = 0.f;
        if (i < 2)                 v = W1n[i * 32 + j];
        else if (i >= 4 && i < 12) v = W1n[(130 + (i - 4)) * 32 + j];
        else if (i >= 12)          v = W1n[(2 + (i - 12)) * 32 + j];
        Wf[OFF_W1NA + idx] = v;
    }
    for (int idx = t; idx < 2048; idx += T) {            // W1NS [32][64]
        int j = idx / 64, k = idx % 64;
        Wf[OFF_W1NS + idx] = W1n[(66 + k) * 32 + j];
    }
    for (int idx = t; idx < 2048; idx += T) Wf[OFF_W2N + idx] = W2n[idx];
    for (int idx = t; idx < 64; idx += T)   Wf[OFF_B2N + idx] = b2n[idx];
    for (int idx = t; idx < 32; idx += T)   Wf[OFF_B1N + idx] = b1n[idx];
    for (int idx = t; idx < 32; idx += T) {
        Wf[OFF_W1POS + 2 * idx + 0] = W1e[2 * 32 + idx];
        Wf[OFF_W1POS + 2 * idx + 1] = W1e[3 * 32 + idx];
    }
    // MFMA B-fragments for W2e (bf16, pre-scaled), 4 N-tiles x 64 lanes x 16B
    for (int idx = t; idx < 256; idx += T) {
        int tt = idx >> 6, l = idx & 63;
        int colv = l & 15, quadv = l >> 4;
        uint4 v;
        unsigned pk[4];
#pragma unroll
        for (int pr = 0; pr < 4; pr++) {
            int j0 = quadv * 8 + 2 * pr;
            float f0 = W2e[j0 * 64 + 16 * tt + colv] * TANH_SCALE;
            float f1 = W2e[(j0 + 1) * 64 + 16 * tt + colv] * TANH_SCALE;
            pk[pr] = f2bf_pair(f0, f1);
        }
        v.x = pk[0]; v.y = pk[1]; v.z = pk[2]; v.w = pk[3];
        fragW2[tt * 64 + l] = v;
    }
}

// ---------------------------------------------------------------------------
// Phase 1: bucket-scatter (blocks < nblkA, LDS-aggregated histogram) +
// per-node precompute (rest):
//   Abf[n][32] bf16 : edge-MLP layer1 src part
//   A2 [n][32] f32  : node-MLP layer1 pos/h/u part (+b1n)
// ---------------------------------------------------------------------------
__global__ __launch_bounds__(256) void k_phase1(
    const float* __restrict__ hbuf, const float* __restrict__ ubuf,
    const float* __restrict__ posbuf, const float* __restrict__ Wf,
    uint4* __restrict__ Abf, float* __restrict__ A2,
    const int* __restrict__ src, const int* __restrict__ dst,
    int* __restrict__ gcnt, unsigned* __restrict__ pairbuf,
    int E, int N, int C, int nblkA) {
    __shared__ int cnt[512], base[512];
    int tid = threadIdx.x;
    if ((int)blockIdx.x < nblkA) {
        for (int i = tid; i < 512; i += 256) cnt[i] = 0;
        __syncthreads();
        int e0 = blockIdx.x * 4096;
#pragma unroll
        for (int k = 0; k < 16; k++) {
            int e = e0 + k * 256 + tid;
            if (e < E) atomicAdd(&cnt[dst[e] >> BUCK_SHIFT], 1);
        }
        __syncthreads();
        for (int i = tid; i < 512; i += 256) {
            int c = cnt[i];
            base[i] = (c > 0) ? atomicAdd(&gcnt[i], c) : 0;
            cnt[i] = 0;
        }
        __syncthreads();
#pragma unroll
        for (int k = 0; k < 16; k++) {
            int e = e0 + k * 256 + tid;
            if (e < E) {
                int d = dst[e];
                int b = d >> BUCK_SHIFT;
                int r = base[b] + atomicAdd(&cnt[b], 1);
                if (r < C)
                    pairbuf[(size_t)b * C + r] =
                        (unsigned)src[e] | ((unsigned)(d & 255) << 20);
            }
        }
        return;
    }
    // ---- per-node precompute ----
    int n = (blockIdx.x - nblkA) * 256 + tid;
    if (n >= N) return;
    float x[76];
    float2 pp = ((const float2*)posbuf)[n];
    x[0] = pp.x; x[1] = pp.y; x[2] = 0.f; x[3] = 0.f;
    const float4* u4 = (const float4*)ubuf;
#pragma unroll
    for (int c = 0; c < 2; c++) {
        float4 uu = u4[(size_t)n * 2 + c];
        int b = 4 + 4 * c;
        x[b] = uu.x; x[b + 1] = uu.y; x[b + 2] = uu.z; x[b + 3] = uu.w;
    }
    const float4* h4 = (const float4*)hbuf;
#pragma unroll
    for (int c = 0; c < 16; c++) {
        float4 hh = h4[(size_t)n * 16 + c];
        int b = 12 + 4 * c;
        x[b] = hh.x; x[b + 1] = hh.y; x[b + 2] = hh.z; x[b + 3] = hh.w;
    }
    float ar[32];
#pragma unroll 1
    for (int j = 0; j < 32; j++) {
        const float* w1 = Wf + OFF_W1ET + j * 76;
        float a0 = Wf[OFF_B1E + j], a1 = 0.f, a2 = 0.f, a3 = 0.f;
#pragma unroll
        for (int i = 0; i < 76; i += 4) {
            a0 = fmaf(x[i + 0], w1[i + 0], a0);
            a1 = fmaf(x[i + 1], w1[i + 1], a1);
            a2 = fmaf(x[i + 2], w1[i + 2], a2);
            a3 = fmaf(x[i + 3], w1[i + 3], a3);
        }
        ar[j] = (a0 + a1) + (a2 + a3);
    }
#pragma unroll
    for (int c = 0; c < 4; c++) {
        uint4 v;
        v.x = f2bf_pair(ar[8 * c + 0], ar[8 * c + 1]);
        v.y = f2bf_pair(ar[8 * c + 2], ar[8 * c + 3]);
        v.z = f2bf_pair(ar[8 * c + 4], ar[8 * c + 5]);
        v.w = f2bf_pair(ar[8 * c + 6], ar[8 * c + 7]);
        Abf[(size_t)n * 4 + c] = v;
    }
    // node-MLP layer1 pos/h/u part (x[2],x[3] are zero -> harmless)
#pragma unroll 1
    for (int j = 0; j < 32; j++) {
        const float* w1 = Wf + OFF_W1NA + j * 76;
        float a0 = Wf[OFF_B1N + j], a1 = 0.f, a2 = 0.f, a3 = 0.f;
#pragma unroll
        for (int i = 0; i < 76; i += 4) {
            a0 = fmaf(x[i + 0], w1[i + 0], a0);
            a1 = fmaf(x[i + 1], w1[i + 1], a1);
            a2 = fmaf(x[i + 2], w1[i + 2], a2);
            a3 = fmaf(x[i + 3], w1[i + 3], a3);
        }
        ar[j] = (a0 + a1) + (a2 + a3);
    }
#pragma unroll
    for (int c = 0; c < 8; c++) {
        float4 v; v.x = ar[4 * c]; v.y = ar[4 * c + 1];
        v.z = ar[4 * c + 2]; v.w = ar[4 * c + 3];
        ((float4*)(A2 + (size_t)n * 32))[c] = v;
    }
}

// ---------------------------------------------------------------------------
// Pass B: one block per bucket. LDS deg/scan -> seg; LDS-cursor scatter ssrc.
// ---------------------------------------------------------------------------
__global__ __launch_bounds__(256) void k_bucketB(
    const unsigned* __restrict__ pairbuf, const int* __restrict__ gcnt,
    int2* __restrict__ seg, int* __restrict__ ssrc, int N, int C) {
    __shared__ int deg[256], scn[256], exc[256], cur[256];
    int b = blockIdx.x, tid = threadIdx.x;
    int cntb = gcnt[b];
    cntb = (cntb < C) ? cntb : C;
    deg[tid] = 0; cur[tid] = 0;
    __syncthreads();
    size_t basep = (size_t)b * C;
    for (int i = tid; i < cntb; i += 256)
        atomicAdd(&deg[pairbuf[basep + i] >> 20], 1);
    __syncthreads();
    scn[tid] = deg[tid];
    __syncthreads();
    for (int st = 1; st < 256; st <<= 1) {
        int add = (tid >= st) ? scn[tid - st] : 0;
        __syncthreads();
        scn[tid] += add;
        __syncthreads();
    }
    int ex = scn[tid] - deg[tid];
    exc[tid] = ex;
    int n = (b << BUCK_SHIFT) + tid;
    if (n < N) {
        int lo = b * C + ex;
        seg[n] = make_int2(lo, lo + deg[tid]);
    }
    __syncthreads();
    for (int i = tid; i < cntb; i += 256) {
        unsigned p = pairbuf[basep + i];
        int l = (int)(p >> 20);
        int slot = exc[l] + atomicAdd(&cur[l], 1);
        ssrc[basep + slot] = (int)(p & 0xFFFFFu);
    }
}

// ---------------------------------------------------------------------------
// Fused edge-MLP + gather + node-MLP. Edge loop identical to R11 (verified
// 69.2us). Epilogue: per node, wave holds the 64-dim sigmoid-sum; node MLP
// computed in-wave via LDS-staged weights; writes out[n][64] directly.
// ---------------------------------------------------------------------------
__global__ __launch_bounds__(256) void fused_edge_node(
    const int2* __restrict__ seg, const int* __restrict__ ssrc,
    const uint4* __restrict__ Abf, const float* __restrict__ posbuf,
    const float* __restrict__ A2, const float* __restrict__ Wf,
    const uint4* __restrict__ fragW2, float* __restrict__ out,
    int N, int npw) {
    __shared__ float w1s[32 * 66];      // W1NS[j][i], pad 66: 2-way max
    __shared__ float w2s[64 * 34];      // W2n^T[k][j], pad 34: 4-way max on b64
    __shared__ float rowbuf[4 * 96];    // per wave: s[64] + y[32]

    int wv = threadIdx.x >> 6;
    int lane = threadIdx.x & 63;
    int col = lane & 15, quad = lane >> 4;

    // stage node-MLP weights into LDS (once per block)
    for (int idx = threadIdx.x; idx < 2048; idx += 256) {
        int j = idx >> 6, i = idx & 63;
        w1s[j * 66 + i] = Wf[OFF_W1NS + idx];
        int k2 = idx >> 5, j2 = idx & 31;
        w2s[k2 * 34 + j2] = Wf[OFF_W2N + j2 * 64 + k2];
    }
    float b2nk = Wf[OFF_B2N + lane];
    __syncthreads();

    union { uint4 u; bf16x8 v; } cvt;
    bf16x8 bfr[4];
#pragma unroll
    for (int t = 0; t < 4; t++) {
        cvt.u = fragW2[t * 64 + lane];
        bfr[t] = cvt.v;
    }
    float c0[4];
#pragma unroll
    for (int t = 0; t < 4; t++) c0[t] = Wf[OFF_B2E + 16 * t + col];
    float wx[8], wy[8];
#pragma unroll
    for (int jj = 0; jj < 8; jj++) {
        float2 wv2 = ((const float2*)(Wf + OFF_W1POS))[quad * 8 + jj];
        wx[jj] = wv2.x; wy[jj] = wv2.y;
    }

    int wid = blockIdx.x * 4 + wv;
    int n0 = wid * npw;
    int n1 = n0 + npw; n1 = (n1 < N) ? n1 : N;
    float* srow = rowbuf + wv * 96;
    float* yrow = srow + 64;
#pragma unroll 1
    for (int n = n0; n < n1; n++) {
        int2 sg = seg[n];
        int lo = sg.x, hi = sg.y, deg = hi - lo;
        float2 pd = ((const float2*)posbuf)[n];
        float padd[8];
#pragma unroll
        for (int jj = 0; jj < 8; jj++)
            padd[jj] = fmaf(pd.x, wx[jj], pd.y * wy[jj]);

        float s0[4] = {0.f, 0.f, 0.f, 0.f};
        if (deg > 0) {
            int te = lo + col;
            te = (te < hi) ? te : (hi - 1);
            uint4 ar = Abf[(size_t)ssrc[te] * 4 + quad];
            int nfull = deg & ~15;
#pragma unroll 1
            for (int b = 0; b < nfull; b += 16) {
                int teN = lo + b + 16 + col;
                teN = (teN < hi) ? teN : (hi - 1);
                uint4 arN = Abf[(size_t)ssrc[teN] * 4 + quad];

                bf16x8 af;
                {
                    float v0 = bf_lo(ar.x) + padd[0], v1 = bf_hi(ar.x) + padd[1];
                    float v2 = bf_lo(ar.y) + padd[2], v3 = bf_hi(ar.y) + padd[3];
                    float v4 = bf_lo(ar.z) + padd[4], v5 = bf_hi(ar.z) + padd[5];
                    float v6 = bf_lo(ar.w) + padd[6], v7 = bf_hi(ar.w) + padd[7];
                    v0 = fmaxf(v0, LRELU_SLOPE * v0); v1 = fmaxf(v1, LRELU_SLOPE * v1);
                    v2 = fmaxf(v2, LRELU_SLOPE * v2); v3 = fmaxf(v3, LRELU_SLOPE * v3);
                    v4 = fmaxf(v4, LRELU_SLOPE * v4); v5 = fmaxf(v5, LRELU_SLOPE * v5);
                    v6 = fmaxf(v6, LRELU_SLOPE * v6); v7 = fmaxf(v7, LRELU_SLOPE * v7);
                    af[0] = (__bf16)v0; af[1] = (__bf16)v1; af[2] = (__bf16)v2; af[3] = (__bf16)v3;
                    af[4] = (__bf16)v4; af[5] = (__bf16)v5; af[6] = (__bf16)v6; af[7] = (__bf16)v7;
                }
#pragma unroll
                for (int t = 0; t < 4; t++) {
                    f32x4 acc = {c0[t], c0[t], c0[t], c0[t]};
                    acc = __builtin_amdgcn_mfma_f32_16x16x32_bf16(af, bfr[t], acc, 0, 0, 0);
                    float u0 = __builtin_amdgcn_exp2f(acc[0]);
                    float u1 = __builtin_amdgcn_exp2f(acc[1]);
                    float u2 = __builtin_amdgcn_exp2f(acc[2]);
                    float u3 = __builtin_amdgcn_exp2f(acc[3]);
                    float q01 = u0 + u1, q23 = u2 + u3;
                    float d01 = fmaf(u0, u1, q01) + 1.f;
                    float d23 = fmaf(u2, u3, q23) + 1.f;
                    s0[t] = fmaf(q01 + 2.f, __builtin_amdgcn_rcpf(d01), s0[t]);
                    s0[t] = fmaf(q23 + 2.f, __builtin_amdgcn_rcpf(d23), s0[t]);
                }
                ar = arN;
            }
            int tail = deg - nfull;
            if (tail) {
                bf16x8 af;
                {
                    float v0 = bf_lo(ar.x) + padd[0], v1 = bf_hi(ar.x) + padd[1];
                    float v2 = bf_lo(ar.y) + padd[2], v3 = bf_hi(ar.y) + padd[3];
                    float v4 = bf_lo(ar.z) + padd[4], v5 = bf_hi(ar.z) + padd[5];
                    float v6 = bf_lo(ar.w) + padd[6], v7 = bf_hi(ar.w) + padd[7];
                    v0 = fmaxf(v0, LRELU_SLOPE * v0); v1 = fmaxf(v1, LRELU_SLOPE * v1);
                    v2 = fmaxf(v2, LRELU_SLOPE * v2); v3 = fmaxf(v3, LRELU_SLOPE * v3);
                    v4 = fmaxf(v4, LRELU_SLOPE * v4); v5 = fmaxf(v5, LRELU_SLOPE * v5);
                    v6 = fmaxf(v6, LRELU_SLOPE * v6); v7 = fmaxf(v7, LRELU_SLOPE * v7);
                    af[0] = (__bf16)v0; af[1] = (__bf16)v1; af[2] = (__bf16)v2; af[3] = (__bf16)v3;
                    af[4] = (__bf16)v4; af[5] = (__bf16)v5; af[6] = (__bf16)v6; af[7] = (__bf16)v7;
                }
                int rowb = quad * 4;
#pragma unroll
                for (int t = 0; t < 4; t++) {
                    f32x4 acc = {c0[t], c0[t], c0[t], c0[t]};
                    acc = __builtin_amdgcn_mfma_f32_16x16x32_bf16(af, bfr[t], acc, 0, 0, 0);
                    float u0 = (rowb + 0 < tail) ? __builtin_amdgcn_exp2f(acc[0]) : 1e30f;
                    float u1 = (rowb + 1 < tail) ? __builtin_amdgcn_exp2f(acc[1]) : 1e30f;
                    float u2 = (rowb + 2 < tail) ? __builtin_amdgcn_exp2f(acc[2]) : 1e30f;
                    float u3 = (rowb + 3 < tail) ? __builtin_amdgcn_exp2f(acc[3]) : 1e30f;
                    float q01 = u0 + u1, q23 = u2 + u3;
                    float d01 = fmaf(u0, u1, q01) + 1.f;
                    float d23 = fmaf(u2, u3, q23) + 1.f;
                    s0[t] = fmaf(q01 + 2.f, __builtin_amdgcn_rcpf(d01), s0[t]);
                    s0[t] = fmaf(q23 + 2.f, __builtin_amdgcn_rcpf(d23), s0[t]);
                }
            }
        }
#pragma unroll
        for (int t = 0; t < 4; t++) {
            s0[t] += __shfl_xor(s0[t], 16);
            s0[t] += __shfl_xor(s0[t], 32);
        }
        // ---- node-MLP epilogue (in-wave) ----
        float fd = (float)deg;
        if (lane < 16) {
#pragma unroll
            for (int t = 0; t < 4; t++)
                srow[16 * t + lane] = fmaf(-2.f, s0[t], fd);
        }
        asm volatile("s_waitcnt lgkmcnt(0)" ::: "memory");
        if (lane < 32) {
            float acc0 = A2[(size_t)n * 32 + lane], acc1 = 0.f;
            const float* wr = w1s + lane * 66;
#pragma unroll
            for (int i = 0; i < 64; i += 2) {
                float2 w = *(const float2*)(wr + i);
                acc0 = fmaf(w.x, srow[i], acc0);
                acc1 = fmaf(w.y, srow[i + 1], acc1);
            }
            float yj = acc0 + acc1;
            yj = fmaxf(yj, LRELU_SLOPE * yj);
            yrow[lane] = yj;
        }
        asm volatile("s_waitcnt lgkmcnt(0)" ::: "memory");
        float ok = b2nk;
        const float* w2r = w2s + lane * 34;
#pragma unroll
        for (int j = 0; j < 32; j += 2) {
            float2 w = *(const float2*)(w2r + j);
            ok = fmaf(w.x, yrow[j], ok);
            ok = fmaf(w.y, yrow[j + 1], ok);
        }
        out[(size_t)n * 64 + lane] = ftanh(ok);
    }
}

// ---------------------------------------------------------------------------
extern "C" void kernel_launch(void* const* d_in, const int* in_sizes, int n_in,
                              void* d_out, int out_size, void* d_ws, size_t ws_size,
                              hipStream_t stream) {
    const float* hbuf   = (const float*)d_in[0];
    const float* ubuf   = (const float*)d_in[1];
    const float* posbuf = (const float*)d_in[2];
    const int* src = (const int*)d_in[3];
    const int* dst = (const int*)d_in[4];

    int N = in_sizes[0] / 64;
    int E = in_sizes[3];
    int NBUCK = (N + 255) >> BUCK_SHIFT;                 // 256-node buckets
    int C = ((2 * ((E + NBUCK - 1) / NBUCK)) + 255) & ~255;  // bucket capacity
    int nblkA = (E + 4095) / 4096;

    char* p = (char*)d_ws;
    auto alloc = [&](size_t bytes) {
        char* r = p;
        p += (bytes + 255) & ~(size_t)255;
        return r;
    };
    float*    Wf      = (float*)alloc(W_TOTAL * 4);
    uint4*    fragW2  = (uint4*)alloc(4 * 64 * 16);
    uint4*    Abf     = (uint4*)alloc((size_t)N * 64);   // bf16 A rows, 64B
    float*    A2      = (float*)alloc((size_t)N * 32 * 4);
    int2*     seg     = (int2*)alloc((size_t)N * 8);
    int*      gcnt    = (int*)alloc((size_t)NBUCK * 4);
    unsigned* pairbuf = (unsigned*)alloc((size_t)NBUCK * C * 4);
    int*      ssrc    = (int*)alloc((size_t)NBUCK * C * 4);

    prep_weights<<<32, 256, 0, stream>>>(
        (const float*)d_in[5], (const float*)d_in[6],
        (const float*)d_in[7], (const float*)d_in[8],
        (const float*)d_in[9], (const float*)d_in[10],
        (const float*)d_in[11], (const float*)d_in[12], Wf, fragW2,
        gcnt, NBUCK);

    int nblkP = nblkA + (N + 255) / 256;
    k_phase1<<<nblkP, 256, 0, stream>>>(
        hbuf, ubuf, posbuf, Wf, Abf, A2, src, dst, gcnt, pairbuf, E, N, C, nblkA);

    k_bucketB<<<NBUCK, 256, 0, stream>>>(pairbuf, gcnt, seg, ssrc, N, C);

    const int FBLK = 1536;                    // 6144 waves, 6 blocks/CU resident
    int npw = (N + FBLK * 4 - 1) / (FBLK * 4);
    fused_edge_node<<<FBLK, 256, 0, stream>>>(
        seg, ssrc, Abf, posbuf, A2, Wf, fragW2, (float*)d_out, N, npw);
}